// Round 5
// baseline (374.642 us; speedup 1.0000x reference)
//
#include <hip/hip_runtime.h>

// Depthwise 2x2 Haar high-pass, stride 1, VALID.
// in:  (B=4, C=128, H=512, W=512) fp32 -> out: (B, C, 511, 511) fp32
// out[y,x] = 0.5*((in[y,x]-in[y,x+1]) - (in[y+1,x]-in[y+1,x+1]))
//
// Round 5: fill-like geometry. 1024 blocks x 1 wave; each wave streams half a
// channel (256 rows) sequentially with 8-row ping-pong batching. One wave
// covers a full 512-col row (64 lanes x 8 cols, 32B/lane); the x+1 neighbor
// comes from a single __shfl_down -> no redundant loads, so non-temporal
// (no-allocate) loads are safe. NT loads+stores avoid L3 allocation (dodges
// evicting the harness's dirty 0xAA fill) and ~2048 deep streams replace
// ~8192 shallow ones (DRAM row-buffer locality).

#define Bn 4
#define Cn 128
#define Hn 512
#define Wn 512
#define OH 511
#define OW 511
#define HALF 256         // output rows per block (half channel)
#define TPB 64           // one wave

typedef float f4 __attribute__((ext_vector_type(4)));
typedef float f4u __attribute__((ext_vector_type(4), aligned(4)));

struct Row {
    f4 a;      // cols 8L .. 8L+3
    f4 b;      // cols 8L+4 .. 8L+7
    float e;   // col 8L+8 (next lane's a.x), garbage on lane 63
};

__device__ __forceinline__ Row load_row(const float* __restrict__ p) {
    Row r;
    r.a = __builtin_nontemporal_load(reinterpret_cast<const f4*>(p));
    r.b = __builtin_nontemporal_load(reinterpret_cast<const f4*>(p + 4));
    r.e = __shfl_down(r.a.x, 1);
    return r;
}

__device__ __forceinline__ void haar8(const Row& t, const Row& b, float* o) {
    const float t9[9] = {t.a.x, t.a.y, t.a.z, t.a.w, t.b.x, t.b.y, t.b.z, t.b.w, t.e};
    const float b9[9] = {b.a.x, b.a.y, b.a.z, b.a.w, b.b.x, b.b.y, b.b.z, b.b.w, b.e};
#pragma unroll
    for (int i = 0; i < 8; ++i)
        o[i] = 0.5f * ((t9[i] - t9[i + 1]) - (b9[i] - b9[i + 1]));
}

__device__ __forceinline__ void store_row(float* __restrict__ op, int lane, const float* o) {
    f4u vA = {o[0], o[1], o[2], o[3]};
    __builtin_nontemporal_store(vA, reinterpret_cast<f4u*>(op));
    if (lane < 63) {
        f4u vB = {o[4], o[5], o[6], o[7]};
        __builtin_nontemporal_store(vB, reinterpret_cast<f4u*>(op + 4));
    } else {
        // lane 63 owns output cols 504..510 only (col 511 doesn't exist)
        __builtin_nontemporal_store(o[4], op + 4);
        __builtin_nontemporal_store(o[5], op + 5);
        __builtin_nontemporal_store(o[6], op + 6);
    }
}

__global__ __launch_bounds__(TPB)
void haar_kernel(const float* __restrict__ in, float* __restrict__ out) {
    const int bx   = blockIdx.x;          // 0 .. 1023
    const int ch   = bx >> 1;             // 0 .. 511
    const int half = bx & 1;
    const int y0   = half * HALF;
    const int lane = threadIdx.x;         // one wave
    const int xi   = lane * 8;

    const float* __restrict__ inCh  = in  + (size_t)ch * Hn * Wn + xi;
    float* __restrict__       outCh = out + (size_t)ch * (OH * OW) + xi;

    Row cur = load_row(inCh + (size_t)y0 * Wn);
    Row A[8], B[8];

#pragma unroll
    for (int i = 0; i < 8; ++i)
        A[i] = load_row(inCh + (size_t)(y0 + 1 + i) * Wn);

    float o[8];

    for (int g = 0; g < 32; g += 2) {
        // burst-load group g+1 into B (input rows y0 + 8*(g+1) + 1 + i, clamped)
#pragma unroll
        for (int i = 0; i < 8; ++i) {
            int yy = y0 + 8 * (g + 1) + 1 + i;
            if (yy > Hn - 1) yy = Hn - 1;
            B[i] = load_row(inCh + (size_t)yy * Wn);
        }

        // compute + store group g from [cur, A]
#pragma unroll
        for (int i = 0; i < 8; ++i) {
            const int y = y0 + 8 * g + i;
            haar8(cur, A[i], o);
            if (y < OH) store_row(outCh + (size_t)y * OW, lane, o);
            cur = A[i];
        }

        // burst-load group g+2 into A
        if (g + 2 < 32) {
#pragma unroll
            for (int i = 0; i < 8; ++i) {
                int yy = y0 + 8 * (g + 2) + 1 + i;
                if (yy > Hn - 1) yy = Hn - 1;
                A[i] = load_row(inCh + (size_t)yy * Wn);
            }
        }

        // compute + store group g+1 from [cur, B]
#pragma unroll
        for (int i = 0; i < 8; ++i) {
            const int y = y0 + 8 * (g + 1) + i;
            haar8(cur, B[i], o);
            if (y < OH) store_row(outCh + (size_t)y * OW, lane, o);
            cur = B[i];
        }
    }
}

extern "C" void kernel_launch(void* const* d_in, const int* in_sizes, int n_in,
                              void* d_out, int out_size, void* d_ws, size_t ws_size,
                              hipStream_t stream) {
    const float* x = (const float*)d_in[0];
    float* out = (float*)d_out;

    dim3 grid(Bn * Cn * 2);   // 1024 single-wave blocks = 4 waves/CU
    dim3 block(TPB);
    haar_kernel<<<grid, block, 0, stream>>>(x, out);
}

// Round 6
// 208.460 us; speedup vs baseline: 1.7972x; 1.7972x over previous
//
#include <hip/hip_runtime.h>

// Depthwise 2x2 Haar high-pass, stride 1, VALID.
// in:  (B=4, C=128, H=512, W=512) fp32 -> out: (B, C, 511, 511) fp32
// out[y,x] = 0.5*((in[y,x]-in[y,x+1]) - (in[y+1,x]-in[y+1,x+1]))
//
// Round 6: LDS-staged aligned write streaming.
// Phase A: each block computes a 16-row output group into LDS [16][512]
//   (padded stride). Per-wave ds_write_b128, one row per instruction,
//   lanes contiguous -> bank-conflict-free.
// Phase B: the group's output is a CONTIGUOUS 16*511-dword span in memory.
//   Threads stream it with stride-1 dword ownership: lane L stores dword
//   j = t + 256k -> 1KB contiguous per wave-instruction, every 64B line
//   fully covered by one instruction -> no partial-line write
//   amplification (round-5 counters showed WRITE_SIZE = 1.77x ideal).
//   LDS read addr = j + j/511 -> banks (L + r) % 32 -> conflict-free.

#define Bn 4
#define Cn 128
#define Hn 512
#define Wn 512
#define OH 511
#define OW 511
#define GR 16          // output rows per group
#define TPB 256

typedef float f4 __attribute__((ext_vector_type(4)));

__global__ __launch_bounds__(TPB)
void haar_kernel(const float* __restrict__ in, float* __restrict__ out) {
    __shared__ float lds[GR * 512];   // [16][512] padded row stride

    const int g  = blockIdx.x;        // 0..31 row group
    const int ch = blockIdx.y;        // 0..511 (b*C + c)
    const int y0 = g * GR;
    const int t  = threadIdx.x;
    const int h  = t >> 7;            // row sub-block 0/1
    const int u  = t & 127;
    const int c0 = u * 4;             // 4 contiguous cols per thread

    const float* __restrict__ inCh = in + (size_t)ch * Hn * Wn;

    // ---- Phase A: compute 16 output rows into LDS ----
    // half h handles output rows y0+8h .. y0+8h+7 (input rows y0+8h .. y0+8h+8)
    f4 R[9]; float E[9];
    const int ecol = (u == 127) ? (c0 + 3) : (c0 + 4);   // col 512 doesn't exist; garbage ok
#pragma unroll
    for (int i = 0; i < 9; ++i) {
        int ys = y0 + 8 * h + i;
        if (ys > Hn - 1) ys = Hn - 1;                    // tail clamp (group 31 only)
        const float* p = inCh + (size_t)ys * Wn;
        R[i] = *reinterpret_cast<const f4*>(p + c0);
        E[i] = p[ecol];
    }
#pragma unroll
    for (int i = 0; i < 8; ++i) {
        f4 o;
        o.x = 0.5f * ((R[i].x - R[i].y) - (R[i + 1].x - R[i + 1].y));
        o.y = 0.5f * ((R[i].y - R[i].z) - (R[i + 1].y - R[i + 1].z));
        o.z = 0.5f * ((R[i].z - R[i].w) - (R[i + 1].z - R[i + 1].w));
        o.w = 0.5f * ((R[i].w - E[i])   - (R[i + 1].w - E[i + 1]));
        *reinterpret_cast<f4*>(&lds[(8 * h + i) * 512 + c0]) = o;
    }
    __syncthreads();

    // ---- Phase B: stream the contiguous output span, dense & aligned ----
    const int spanRows = (OH - y0 < GR) ? (OH - y0) : GR;   // 16, or 15 for group 31
    const int nspan = spanRows * OW;                         // dwords in span
    float* __restrict__ outSpan = out + (size_t)ch * (OH * OW) + (size_t)y0 * OW;

#pragma unroll
    for (int k = 0; k < 32; ++k) {
        const int j = t + 256 * k;                 // dword index in span
        if (j < nspan) {
            const int r = (int)((unsigned)j / 511u);   // source row in LDS
            __builtin_nontemporal_store(lds[j + r], outSpan + j);
        }
    }
}

extern "C" void kernel_launch(void* const* d_in, const int* in_sizes, int n_in,
                              void* d_out, int out_size, void* d_ws, size_t ws_size,
                              hipStream_t stream) {
    const float* x = (const float*)d_in[0];
    float* out = (float*)d_out;

    dim3 grid(32, Bn * Cn);   // 32 row-groups x 512 channels
    dim3 block(TPB);
    haar_kernel<<<grid, block, 0, stream>>>(x, out);
}

// Round 7
// 192.519 us; speedup vs baseline: 1.9460x; 1.0828x over previous
//
#include <hip/hip_runtime.h>

// Depthwise 2x2 Haar high-pass, stride 1, VALID.
// in:  (B=4, C=128, H=512, W=512) fp32 -> out: (B, C, 511, 511) fp32
// out[y,x] = 0.5*((in[y,x]-in[y,x+1]) - (in[y+1,x]-in[y+1,x+1]))
//
// Round 7: round-6 structure (LDS-staged dense output streaming) with
//  - GR=32 (halo re-read 6.4% -> 3.1%), TPB=512, LDS 64KB, 2 blocks/CU
//  - phase B: 16B-ALIGNED nontemporal dwordx4 stores. The span's flat dword
//    base F = ch*261121 + y0*511 has F%4 == ch%4, so a head of (4-F%4)%4
//    scalar dwords aligns the quad grid; tail handled scalar. 4x fewer
//    store instructions than round 6's per-dword streaming.
//  - LDS layout [32][512] (row stride 512): span element j lives at
//    lds[j + j/511]; quad reads are 4 x ds_read_b32 (4-way bank alias,
//    1.58x -- immaterial, LDS traffic is tiny vs HBM).

#define Bn 4
#define Cn 128
#define Hn 512
#define Wn 512
#define OH 511
#define OW 511
#define GR 32          // output rows per group
#define TPB 512

typedef float f4 __attribute__((ext_vector_type(4)));

__global__ __launch_bounds__(TPB)
void haar_kernel(const float* __restrict__ in, float* __restrict__ out) {
    __shared__ float lds[GR * 512];   // 64 KB

    const int g  = blockIdx.x;        // 0..15 row group
    const int ch = blockIdx.y;        // 0..511 (b*C + c)
    const int y0 = g * GR;
    const int t  = threadIdx.x;
    const int h  = t >> 7;            // quarter 0..3 -> 8 output rows each
    const int u  = t & 127;
    const int c0 = u * 4;             // 4 contiguous cols per thread

    const float* __restrict__ inCh = in + (size_t)ch * Hn * Wn;

    // ---- Phase A: compute 32 output rows into LDS ----
    // quarter h: output rows y0+8h .. y0+8h+7 (input rows y0+8h .. y0+8h+8)
    f4 R[9]; float E[9];
    const int ecol = (u == 127) ? (c0 + 3) : (c0 + 4);   // col 512 absent; value unused there
#pragma unroll
    for (int i = 0; i < 9; ++i) {
        int ys = y0 + 8 * h + i;
        if (ys > Hn - 1) ys = Hn - 1;                    // tail clamp (last group only)
        const float* p = inCh + (size_t)ys * Wn;
        R[i] = *reinterpret_cast<const f4*>(p + c0);
        E[i] = p[ecol];
    }
#pragma unroll
    for (int i = 0; i < 8; ++i) {
        f4 o;
        o.x = 0.5f * ((R[i].x - R[i].y) - (R[i + 1].x - R[i + 1].y));
        o.y = 0.5f * ((R[i].y - R[i].z) - (R[i + 1].y - R[i + 1].z));
        o.z = 0.5f * ((R[i].z - R[i].w) - (R[i + 1].z - R[i + 1].w));
        o.w = 0.5f * ((R[i].w - E[i])   - (R[i + 1].w - E[i + 1]));
        *reinterpret_cast<f4*>(&lds[(8 * h + i) * 512 + c0]) = o;
    }
    __syncthreads();

    // ---- Phase B: stream the contiguous span with aligned NT dwordx4 ----
    const int spanRows = (OH - y0 < GR) ? (OH - y0) : GR;   // 32 (31 for last group)
    const int nspan = spanRows * OW;                         // dwords in span
    const unsigned F = (unsigned)ch * 261121u + (unsigned)y0 * 511u;  // flat dword base
    float* __restrict__ outSpan = out + F;
    const int s0 = (4 - (int)(F & 3u)) & 3;                  // head dwords to align quads

    // head (<=3 dwords)
    if (t < s0 && t < nspan)
        __builtin_nontemporal_store(lds[t], outSpan + t);    // j<3 -> row 0, lds[j]

    const int qn = (nspan - s0) >> 2;                        // aligned quads
#pragma unroll
    for (int k = 0; k < 8; ++k) {
        const int q = t + TPB * k;
        if (q < qn) {
            const int j0 = s0 + 4 * q;
            f4 v;
#pragma unroll
            for (int m = 0; m < 4; ++m) {
                const unsigned jj = (unsigned)(j0 + m);
                v[m] = lds[jj + jj / 511u];
            }
            __builtin_nontemporal_store(v, reinterpret_cast<f4*>(outSpan + j0));
        }
    }

    // tail (<=3 dwords)
    const int tl0 = s0 + 4 * qn;
    const int tail = nspan - tl0;
    if (t < tail) {
        const unsigned jj = (unsigned)(tl0 + t);
        __builtin_nontemporal_store(lds[jj + jj / 511u], outSpan + jj);
    }
}

extern "C" void kernel_launch(void* const* d_in, const int* in_sizes, int n_in,
                              void* d_out, int out_size, void* d_ws, size_t ws_size,
                              hipStream_t stream) {
    const float* x = (const float*)d_in[0];
    float* out = (float*)d_out;

    dim3 grid(Hn / GR, Bn * Cn);   // (16, 512)
    dim3 block(TPB);
    haar_kernel<<<grid, block, 0, stream>>>(x, out);
}